// Round 1
// baseline (597.172 us; speedup 1.0000x reference)
//
#include <hip/hip_runtime.h>

typedef __bf16 bf16_t;
typedef __bf16 bf16x8 __attribute__((ext_vector_type(8)));
typedef __bf16 bf16x4 __attribute__((ext_vector_type(4)));
typedef float f32x4 __attribute__((ext_vector_type(4)));

#define MFMA16(A_, B_, C_) __builtin_amdgcn_mfma_f32_16x16x32_bf16((A_), (B_), (C_), 0, 0, 0)

__device__ __forceinline__ void gload_lds16(const bf16_t* g, bf16_t* l) {
  __builtin_amdgcn_global_load_lds(
      (const __attribute__((address_space(1))) void*)g,
      (__attribute__((address_space(3))) void*)l, 16, 0, 0);
}

// fp32 -> bf16, 4 elements/thread
__global__ __launch_bounds__(256) void k_convert(const float* __restrict__ in,
                                                 bf16_t* __restrict__ out, int n4) {
  int i = blockIdx.x * 256 + threadIdx.x;
  if (i >= n4) return;
  float4 v = ((const float4*)in)[i];
  bf16x4 o;
  o[0] = (__bf16)v.x; o[1] = (__bf16)v.y; o[2] = (__bf16)v.z; o[3] = (__bf16)v.w;
  *(bf16x4*)(out + (size_t)i * 4) = o;
}

// out[c][r] = (bf16) in[r][c];  in is [R][C] fp32. 64x64 tiles, 256 threads.
__global__ __launch_bounds__(256) void k_transpose(const float* __restrict__ in,
                                                   bf16_t* __restrict__ out, int R, int C) {
  __shared__ float tile[64][65];
  int tx = threadIdx.x & 63;
  int ty = threadIdx.x >> 6;  // 0..3
  int bc = blockIdx.x * 64;
  int br = blockIdx.y * 64;
#pragma unroll
  for (int i = ty; i < 64; i += 4)
    tile[i][tx] = in[(size_t)(br + i) * C + bc + tx];
  __syncthreads();
#pragma unroll
  for (int i = ty; i < 64; i += 4)
    out[(size_t)(bc + i) * R + br + tx] = (bf16_t)tile[tx][i];
}

// block-split row permutation: original token row -> attention-layout row
__device__ __forceinline__ int permrow(int r) {
  int b  = r >> 12;        // batch
  int l  = r & 4095;
  int ix = (l >> 11) & 1;
  int sx = (l >> 6) & 31;
  int iy = (l >> 5) & 1;
  int sy = l & 31;
  return (b << 12) + (ix << 11) + (iy << 10) + (sx << 5) + sy;
}

// C[M][N] = A[M][K] * B^T[N][K], bf16 in, 128x128 tile, BK=64, 4 waves.
// MODE 0: fused QKV (N = 2048 | 512 | 512), bf16 out with row permutation.
// MODE 1: fp32 out, straight rows (N = 2048).
template <int MODE>
__global__ __launch_bounds__(256, 2) void k_gemm(
    const bf16_t* __restrict__ A,
    const bf16_t* __restrict__ B0, const bf16_t* __restrict__ B1,
    const bf16_t* __restrict__ B2,
    bf16_t* __restrict__ Cq, bf16_t* __restrict__ Ck, bf16_t* __restrict__ Cv,
    float* __restrict__ Cf) {
  const int K = 2048;
  int bid = blockIdx.x;
  int tm = bid & 63;   // M/128 = 64
  int tn = bid >> 6;

  const bf16_t* Bp;
  int brow;
  if (MODE == 0) {
    if (tn < 16)      { Bp = B0; brow = tn << 7; }
    else if (tn < 20) { Bp = B1; brow = (tn - 16) << 7; }
    else              { Bp = B2; brow = (tn - 20) << 7; }
  } else {
    Bp = B0; brow = tn << 7;
  }

  __shared__ bf16_t As[128 * 64];
  __shared__ bf16_t Bs[128 * 64];

  int tid = threadIdx.x;
  int lane = tid & 63;
  int w = tid >> 6;
  int wm = w >> 1, wn = w & 1;
  int g16 = lane >> 4, cl = lane & 15;
  int lrow = lane >> 3, lcol = (lane & 7) << 3;

  const bf16_t* ag = A + (size_t)(tm * 128 + w * 32 + lrow) * K + lcol;
  const bf16_t* bg = Bp + (size_t)(brow + w * 32 + lrow) * K + lcol;
  bf16_t* al = As + (w * 32) * 64;
  bf16_t* bl = Bs + (w * 32) * 64;

  f32x4 acc[4][4];
#pragma unroll
  for (int i = 0; i < 4; ++i)
#pragma unroll
    for (int j = 0; j < 4; ++j) acc[i][j] = (f32x4)(0.0f);

  for (int kt = 0; kt < K / 64; ++kt) {
#pragma unroll
    for (int i = 0; i < 4; ++i) {
      gload_lds16(ag + (size_t)i * 8 * K + kt * 64, al + i * 8 * 64);
      gload_lds16(bg + (size_t)i * 8 * K + kt * 64, bl + i * 8 * 64);
    }
    __syncthreads();  // drains vmcnt (global_load_lds) + cross-wave visibility

    bf16x8 af[4][2], bfr[4][2];
#pragma unroll
    for (int mi = 0; mi < 4; ++mi)
#pragma unroll
      for (int kk = 0; kk < 2; ++kk) {
        af[mi][kk]  = *(const bf16x8*)&As[(wm * 64 + mi * 16 + cl) * 64 + kk * 32 + g16 * 8];
        bfr[mi][kk] = *(const bf16x8*)&Bs[(wn * 64 + mi * 16 + cl) * 64 + kk * 32 + g16 * 8];
      }
#pragma unroll
    for (int mi = 0; mi < 4; ++mi)
#pragma unroll
      for (int ni = 0; ni < 4; ++ni)
#pragma unroll
        for (int kk = 0; kk < 2; ++kk)
          acc[mi][ni] = MFMA16(af[mi][kk], bfr[ni][kk], acc[mi][ni]);
    __syncthreads();  // all reads done before next stage overwrites
  }

#pragma unroll
  for (int mi = 0; mi < 4; ++mi) {
#pragma unroll
    for (int rr = 0; rr < 4; ++rr) {
      int r = tm * 128 + wm * 64 + mi * 16 + g16 * 4 + rr;
      if (MODE == 0) {
        int rp = permrow(r);
#pragma unroll
        for (int ni = 0; ni < 4; ++ni) {
          int c = (tn << 7) + wn * 64 + ni * 16 + cl;
          float v = acc[mi][ni][rr];
          if (c < 2048)      Cq[(size_t)rp * 2048 + c] = (bf16_t)v;
          else if (c < 2560) Ck[(size_t)rp * 512 + (c - 2048)] = (bf16_t)v;
          else               Cv[(size_t)rp * 512 + (c - 2560)] = (bf16_t)v;
        }
      } else {
#pragma unroll
        for (int ni = 0; ni < 4; ++ni) {
          int c = (tn << 7) + wn * 64 + ni * 16 + cl;
          Cf[(size_t)r * 2048 + c] = acc[mi][ni][rr];
        }
      }
    }
  }
}

// Flash-style block attention. Grid: qc(8) x h(32) x n(8). WG = 4 waves,
// each wave owns 32 q-rows (128/WG). KV iterated in tiles of 128.
__global__ __launch_bounds__(256, 2) void k_attn(
    const bf16_t* __restrict__ Qp, const bf16_t* __restrict__ Kp,
    const bf16_t* __restrict__ Vp, bf16_t* __restrict__ O) {
  int bid = blockIdx.x;
  int qc = bid & 7;
  int h  = (bid >> 3) & 31;
  int n  = bid >> 8;
  int kvh = h >> 2;  // GQA: query head h -> kv head h//4

  __shared__ bf16_t Ks[128 * 72];       // [kv][d], +8 pad
  __shared__ bf16_t Vt[64 * 136];       // [d][kv], XOR-swizzled columns
  __shared__ bf16_t Ps[4 * 32 * 136];   // per-wave P [32][128], stride 136

  int tid = threadIdx.x, lane = tid & 63, w = tid >> 6;
  int g16 = lane >> 4, cl = lane & 15;

  int qrow0 = n * 1024 + qc * 128 + w * 32;
  bf16x8 qf[2][2];
#pragma unroll
  for (int mi = 0; mi < 2; ++mi)
#pragma unroll
    for (int kc = 0; kc < 2; ++kc)
      qf[mi][kc] = *(const bf16x8*)&Qp[(size_t)(qrow0 + mi * 16 + cl) * 2048 +
                                       h * 64 + kc * 32 + g16 * 8];

  f32x4 o_acc[2][4];
  float m_run[2][4], l_run[2][4];
#pragma unroll
  for (int mi = 0; mi < 2; ++mi) {
#pragma unroll
    for (int cf = 0; cf < 4; ++cf) o_acc[mi][cf] = (f32x4)(0.0f);
#pragma unroll
    for (int rr = 0; rr < 4; ++rr) { m_run[mi][rr] = -1e30f; l_run[mi][rr] = 0.0f; }
  }

  bf16_t* Pw = &Ps[w * 32 * 136];
  const float sc = 0.125f;  // D^-0.5

  for (int it = 0; it < 8; ++it) {
    int kvbase = n * 1024 + it * 128;
    __syncthreads();  // previous iteration's LDS reads complete
    // stage K [128][64] (padded rows) and V transposed [64][128] (XOR swizzle)
#pragma unroll
    for (int j = 0; j < 4; ++j) {
      int idx = j * 256 + tid;
      int i = idx >> 3, c = idx & 7;
      const bf16_t* kvsrc = Kp + (size_t)(kvbase + i) * 512 + kvh * 64 + c * 8;
      bf16x8 kv8 = *(const bf16x8*)kvsrc;
      *(bf16x8*)&Ks[i * 72 + c * 8] = kv8;
      const bf16_t* vsrc = Vp + (size_t)(kvbase + i) * 512 + kvh * 64 + c * 8;
      bf16x8 vv8 = *(const bf16x8*)vsrc;
      int isw = i ^ (c << 4);  // bank/bijective column swizzle per 8-row stripe of d
#pragma unroll
      for (int e = 0; e < 8; ++e)
        Vt[(c * 8 + e) * 136 + isw] = vv8[e];
    }
    __syncthreads();

    // S = Q K^T  (per wave: 32 q-rows x 128 kv)
    f32x4 s[2][8];
#pragma unroll
    for (int mi = 0; mi < 2; ++mi)
#pragma unroll
      for (int cb = 0; cb < 8; ++cb) s[mi][cb] = (f32x4)(0.0f);
#pragma unroll
    for (int cb = 0; cb < 8; ++cb) {
      bf16x8 kf0 = *(const bf16x8*)&Ks[(cb * 16 + cl) * 72 + g16 * 8];
      bf16x8 kf1 = *(const bf16x8*)&Ks[(cb * 16 + cl) * 72 + 32 + g16 * 8];
#pragma unroll
      for (int mi = 0; mi < 2; ++mi) {
        s[mi][cb] = MFMA16(qf[mi][0], kf0, s[mi][cb]);
        s[mi][cb] = MFMA16(qf[mi][1], kf1, s[mi][cb]);
      }
    }

    // online softmax: rows live at (g16*4+rr), cols across the 16-lane group
#pragma unroll
    for (int mi = 0; mi < 2; ++mi) {
#pragma unroll
      for (int rr = 0; rr < 4; ++rr) {
        float mx = -1e30f;
#pragma unroll
        for (int cb = 0; cb < 8; ++cb) mx = fmaxf(mx, s[mi][cb][rr]);
        mx *= sc;
#pragma unroll
        for (int off = 1; off < 16; off <<= 1)
          mx = fmaxf(mx, __shfl_xor(mx, off));
        float mold = m_run[mi][rr];
        float mnew = fmaxf(mold, mx);
        float resc = __expf(mold - mnew);
        m_run[mi][rr] = mnew;
        float rsum = 0.0f;
#pragma unroll
        for (int cb = 0; cb < 8; ++cb) {
          float p = __expf(fmaf(sc, s[mi][cb][rr], -mnew));
          s[mi][cb][rr] = p;
          rsum += p;
        }
#pragma unroll
        for (int off = 1; off < 16; off <<= 1)
          rsum += __shfl_xor(rsum, off);
        l_run[mi][rr] = l_run[mi][rr] * resc + rsum;
#pragma unroll
        for (int cf = 0; cf < 4; ++cf) o_acc[mi][cf][rr] *= resc;
      }
    }

    // P -> LDS (bf16), colblock order staggered by lane-group to spread banks
#pragma unroll
    for (int mi = 0; mi < 2; ++mi)
#pragma unroll
      for (int cbx = 0; cbx < 8; ++cbx) {
        int cb = (cbx + g16) & 7;
#pragma unroll
        for (int rr = 0; rr < 4; ++rr)
          Pw[(mi * 16 + g16 * 4 + rr) * 136 + cb * 16 + cl] = (bf16_t)s[mi][cb][rr];
      }
    __syncthreads();

    // O += P V
#pragma unroll
    for (int kc = 0; kc < 4; ++kc) {
      bf16x8 pa0 = *(const bf16x8*)&Pw[cl * 136 + kc * 32 + g16 * 8];
      bf16x8 pa1 = *(const bf16x8*)&Pw[(16 + cl) * 136 + kc * 32 + g16 * 8];
#pragma unroll
      for (int cf = 0; cf < 4; ++cf) {
        int d = cf * 16 + cl;
        int xr = ((d >> 3) & 7) << 4;
        bf16x8 vf = *(const bf16x8*)&Vt[d * 136 + ((kc * 32 + g16 * 8) ^ xr)];
        o_acc[0][cf] = MFMA16(pa0, vf, o_acc[0][cf]);
        o_acc[1][cf] = MFMA16(pa1, vf, o_acc[1][cf]);
      }
    }
  }

  // write O (attention-layout row == GEMM2 row == output token row)
#pragma unroll
  for (int mi = 0; mi < 2; ++mi)
#pragma unroll
    for (int rr = 0; rr < 4; ++rr) {
      float inv = 1.0f / l_run[mi][rr];
      int row = qrow0 + mi * 16 + g16 * 4 + rr;
#pragma unroll
      for (int cf = 0; cf < 4; ++cf)
        O[(size_t)row * 2048 + h * 64 + cf * 16 + cl] =
            (bf16_t)(o_acc[mi][cf][rr] * inv);
    }
}

extern "C" void kernel_launch(void* const* d_in, const int* in_sizes, int n_in,
                              void* d_out, int out_size, void* d_ws, size_t ws_size,
                              hipStream_t stream) {
  const float* X  = (const float*)d_in[0];
  const float* Wq = (const float*)d_in[1];
  const float* Wk = (const float*)d_in[2];
  const float* Wv = (const float*)d_in[3];
  const float* Wo = (const float*)d_in[4];
  float* out = (float*)d_out;

  char* ws = (char*)d_ws;
  const size_t MB = 1024 * 1024;
  bf16_t* Xb  = (bf16_t*)(ws + 0);        // [8192][2048]  32 MB
  bf16_t* WqT = (bf16_t*)(ws + 32 * MB);  // [2048][2048]   8 MB
  bf16_t* WkT = (bf16_t*)(ws + 40 * MB);  // [512][2048]    2 MB
  bf16_t* WvT = (bf16_t*)(ws + 42 * MB);  // [512][2048]    2 MB
  bf16_t* WoT = (bf16_t*)(ws + 44 * MB);  // [2048][2048]   8 MB
  bf16_t* Qp  = (bf16_t*)(ws + 52 * MB);  // [8192][2048]  32 MB (permuted rows)
  bf16_t* Kp  = (bf16_t*)(ws + 84 * MB);  // [8192][512]    8 MB
  bf16_t* Vp  = (bf16_t*)(ws + 92 * MB);  // [8192][512]    8 MB
  bf16_t* Ob  = (bf16_t*)(ws + 100 * MB); // [8192][2048]  32 MB

  k_convert<<<16384, 256, 0, stream>>>(X, Xb, 4194304);
  k_transpose<<<dim3(32, 32), 256, 0, stream>>>(Wq, WqT, 2048, 2048);
  k_transpose<<<dim3(8, 32), 256, 0, stream>>>(Wk, WkT, 2048, 512);
  k_transpose<<<dim3(8, 32), 256, 0, stream>>>(Wv, WvT, 2048, 512);
  k_transpose<<<dim3(32, 32), 256, 0, stream>>>(Wo, WoT, 2048, 2048);

  k_gemm<0><<<1536, 256, 0, stream>>>(Xb, WqT, WkT, WvT, Qp, Kp, Vp, nullptr);
  k_attn<<<2048, 256, 0, stream>>>(Qp, Kp, Vp, Ob);
  k_gemm<1><<<1024, 256, 0, stream>>>(Ob, WoT, nullptr, nullptr, nullptr, nullptr,
                                      nullptr, out);
}